// Round 1
// baseline (217.503 us; speedup 1.0000x reference)
//
#include <hip/hip_runtime.h>
#include <math.h>

#define K_SIZE 41

// out[k] = base[k % 41], where base[i] = max over j with |(-20+j)| <= scale of
// padded[(i+j) % 41], padded = input[a : a+41].
// Write-BW-bound: 134 MB of float4 stores; input read is 164 bytes (L2-cached
// per block, redundant recompute of base per block is ~900 fmax, negligible).
__global__ void __launch_bounds__(256)
FlatDilation1D_kernel(const float* __restrict__ in,
                      const float* __restrict__ scale_p,
                      float* __restrict__ out,
                      long long n, long long a, long long n4) {
    __shared__ float s_pad[K_SIZE];
    __shared__ float s_ext[K_SIZE + 3];  // base[] extended so r..r+3 never wraps

    const int tid = threadIdx.x;

    if (tid < K_SIZE) {
        s_pad[tid] = in[a + tid];
    }
    __syncthreads();

    if (tid < K_SIZE) {
        const float scale = *scale_p;
        float m = -INFINITY;
        #pragma unroll
        for (int j = 0; j < K_SIZE; ++j) {
            const float z = -20.0f + (float)j;            // exact in fp32
            if (fabsf(z) <= scale) {
                int idx = tid + j;
                if (idx >= K_SIZE) idx -= K_SIZE;
                m = fmaxf(m, s_pad[idx]);
            }
        }
        s_ext[tid] = m;
    }
    __syncthreads();
    if (tid < 3) {
        s_ext[K_SIZE + tid] = s_ext[tid];                 // wrap-around copies
    }
    __syncthreads();

    // Vectorized stores: thread q writes out[4q .. 4q+3].
    const long long q = (long long)blockIdx.x * blockDim.x + tid;
    if (q < n4) {
        // r = (4q) mod 41 in 32-bit (q < 2^29 here) -> compiler magic-multiply
        const unsigned int r = (4u * (unsigned int)q) % 41u;
        float4 v;
        v.x = s_ext[r];
        v.y = s_ext[r + 1];
        v.z = s_ext[r + 2];
        v.w = s_ext[r + 3];
        reinterpret_cast<float4*>(out)[q] = v;
    }

    // Tail: n % 4 leftover elements (n = 33554433 -> exactly 1).
    if (blockIdx.x == 0) {
        const long long tail_start = n4 * 4;
        const long long k = tail_start + tid;
        if (k < n) {
            out[k] = s_ext[(unsigned int)(k % K_SIZE)];
        }
    }
}

extern "C" void kernel_launch(void* const* d_in, const int* in_sizes, int n_in,
                              void* d_out, int out_size, void* d_ws, size_t ws_size,
                              hipStream_t stream) {
    const float* in      = (const float*)d_in[0];
    const float* scale_p = (const float*)d_in[1];
    float* out           = (float*)d_out;

    const long long n = (long long)in_sizes[0];

    // a = -((K - n) // 2 + 2), Python floor-division semantics.
    const long long missing = (long long)K_SIZE - n;
    long long fd = missing / 2;
    if ((missing % 2 != 0) && (missing < 0)) fd -= 1;   // floor for negatives
    const long long a = -(fd + 2);

    const long long n4 = n / 4;                          // full float4 stores
    const int block = 256;
    const long long grid = (n4 + block - 1) / block;

    FlatDilation1D_kernel<<<(dim3)(unsigned int)grid, block, 0, stream>>>(
        in, scale_p, out, n, a, n4);
}

// Round 2
// 206.244 us; speedup vs baseline: 1.0546x; 1.0546x over previous
//
#include <hip/hip_runtime.h>
#include <math.h>

#define K_SIZE 41

// Stage 1: one block computes base[41] and emits the float4-phase pattern:
// pattern4[m] = { base[(4m+0)%41], ..., base[(4m+3)%41] }, m in [0,41).
// Since 4*41 == 0 (mod 41), output float4 #q == pattern4[q % 41].
__global__ void __launch_bounds__(64)
FlatDilation1D_pattern_kernel(const float* __restrict__ in,
                              const float* __restrict__ scale_p,
                              float4* __restrict__ pat4,
                              long long a) {
    __shared__ float s_pad[K_SIZE];
    __shared__ float s_ext[K_SIZE + 3];
    const int tid = threadIdx.x;

    if (tid < K_SIZE) s_pad[tid] = in[a + tid];
    __syncthreads();

    if (tid < K_SIZE) {
        const float scale = *scale_p;
        float m = -INFINITY;
        #pragma unroll
        for (int j = 0; j < K_SIZE; ++j) {
            const float z = -20.0f + (float)j;        // exact in fp32
            if (fabsf(z) <= scale) {
                int idx = tid + j;
                if (idx >= K_SIZE) idx -= K_SIZE;
                m = fmaxf(m, s_pad[idx]);
            }
        }
        s_ext[tid] = m;
    }
    __syncthreads();
    if (tid < 3) s_ext[K_SIZE + tid] = s_ext[tid];
    __syncthreads();

    if (tid < K_SIZE) {
        const unsigned int r = (4u * (unsigned int)tid) % 41u;
        float4 v;
        v.x = s_ext[r];
        v.y = s_ext[r + 1];
        v.z = s_ext[r + 2];
        v.w = s_ext[r + 3];
        pat4[tid] = v;
    }
}

// Stage 2: pure streaming store. Each block owns a contiguous region of
// STORES_PER_THREAD*256 float4s; one ds_read_b128 + one global_store_dwordx4
// per 16 bytes. Phase advances by (256 % 41) == 10 per iteration.
#define S2_BLOCK 256
#define STORES_PER_THREAD 16

__global__ void __launch_bounds__(S2_BLOCK)
FlatDilation1D_store_kernel(const float4* __restrict__ pat4,
                            float4* __restrict__ out4,
                            float* __restrict__ out,
                            long long n, long long n4) {
    __shared__ float4 s_pat4[K_SIZE];
    const int tid = threadIdx.x;

    if (tid < K_SIZE) s_pat4[tid] = pat4[tid];
    __syncthreads();

    const long long q0 = (long long)blockIdx.x * (S2_BLOCK * STORES_PER_THREAD) + tid;
    unsigned int r = (unsigned int)((q0) % 41u);   // q0 < 2^33, use ull mod
    // (use 64-bit mod for safety; compiler strength-reduces)
    r = (unsigned int)(((unsigned long long)q0) % 41ull);

    long long q = q0;
    #pragma unroll
    for (int t = 0; t < STORES_PER_THREAD; ++t) {
        if (q < n4) {
            out4[q] = s_pat4[r];
        }
        q += S2_BLOCK;
        r += 10u;                 // 256 % 41 == 10
        if (r >= 41u) r -= 41u;
    }

    // Tail: n % 4 leftover scalar elements (n = 33554433 -> exactly 1).
    // s_pat4 viewed flat is base[j % 41] for j in [0,164).
    if (blockIdx.x == 0 && tid == 0) {
        const float* s_flat = (const float*)s_pat4;
        for (long long k = n4 * 4; k < n; ++k) {
            out[k] = s_flat[(unsigned int)(((unsigned long long)k) % 41ull)];
        }
    }
}

extern "C" void kernel_launch(void* const* d_in, const int* in_sizes, int n_in,
                              void* d_out, int out_size, void* d_ws, size_t ws_size,
                              hipStream_t stream) {
    const float* in      = (const float*)d_in[0];
    const float* scale_p = (const float*)d_in[1];
    float* out           = (float*)d_out;
    float4* pat4         = (float4*)d_ws;   // 656 bytes used

    const long long n = (long long)in_sizes[0];

    // a = -((K - n) // 2 + 2), Python floor-division semantics.
    const long long missing = (long long)K_SIZE - n;
    long long fd = missing / 2;
    if ((missing % 2 != 0) && (missing < 0)) fd -= 1;
    const long long a = -(fd + 2);

    const long long n4 = n / 4;

    FlatDilation1D_pattern_kernel<<<1, 64, 0, stream>>>(in, scale_p, pat4, a);

    const long long per_block = (long long)S2_BLOCK * STORES_PER_THREAD;
    const long long grid = (n4 + per_block - 1) / per_block;
    FlatDilation1D_store_kernel<<<(dim3)(unsigned int)grid, S2_BLOCK, 0, stream>>>(
        pat4, (float4*)out, out, n, n4);
}

// Round 4
// 202.604 us; speedup vs baseline: 1.0735x; 1.0180x over previous
//
#include <hip/hip_runtime.h>
#include <math.h>

#define K_SIZE 41
#define BLOCK 256
#define GRID 2050                       // 2050*256 = 524800 ≡ 0 (mod 41)
#define STRIDE ((long long)BLOCK * GRID)

// out[k] = base[k % 41]; base[i] = max_{j:|j-20|<=scale} in[a + (i+j)%41].
// Store-BW-bound. Per-thread phase r = (4q) mod 41 is invariant because the
// float4-index stride (524800) is ≡ 0 (mod 41) -> pattern value lives in
// 4 VGPRs and the hot loop is one global_store_dwordx4 + one add.
__global__ void __launch_bounds__(BLOCK)
FlatDilation1D_kernel(const float* __restrict__ in,
                      const float* __restrict__ scale_p,
                      float4* __restrict__ out4,
                      float* __restrict__ out,
                      long long n, long long n4, long long a,
                      int full_iters) {
    __shared__ float s_pad[K_SIZE];
    __shared__ float s_ext[K_SIZE + 3];
    const int tid = threadIdx.x;

    // ---- preamble: build base[] (+3 wrap entries), one wave does the work ----
    if (tid < K_SIZE) s_pad[tid] = in[a + tid];
    __syncthreads();
    if (tid < K_SIZE) {
        const float scale = *scale_p;
        float m = -INFINITY;
        #pragma unroll
        for (int j = 0; j < K_SIZE; ++j) {
            const float z = -20.0f + (float)j;          // exact in fp32
            if (fabsf(z) <= scale) {
                int idx = tid + j;
                if (idx >= K_SIZE) idx -= K_SIZE;
                m = fmaxf(m, s_pad[idx]);
            }
        }
        s_ext[tid] = m;
    }
    __syncthreads();
    if (tid < 3) s_ext[K_SIZE + tid] = s_ext[tid];
    __syncthreads();

    // ---- per-thread constant pattern value ----
    long long q = (long long)blockIdx.x * BLOCK + tid;  // first float4 index
    // element index of this float4 is 4q -> phase r = (4q) mod 41.
    // q0 < 524800 so 4*q0 fits comfortably in 32 bits.
    const unsigned int r = (4u * (unsigned int)q) % 41u;  // invariant across iters
    float4 v;
    v.x = s_ext[r];
    v.y = s_ext[r + 1];
    v.z = s_ext[r + 2];
    v.w = s_ext[r + 3];

    // ---- hot loop: pure streaming stores, no guards, no LDS ----
    for (int it = 0; it < full_iters; ++it) {           // provably in-bounds
        out4[q] = v;
        q += STRIDE;
    }
    while (q < n4) {                                    // last partial sweep
        out4[q] = v;
        q += STRIDE;
    }

    // ---- scalar tail (n % 4 elements; 1 for this N) ----
    if (blockIdx.x == 0 && tid == 0) {
        for (long long k = n4 * 4; k < n; ++k) {
            out[k] = s_ext[(unsigned int)(((unsigned long long)k) % 41ull)];
        }
    }
}

extern "C" void kernel_launch(void* const* d_in, const int* in_sizes, int n_in,
                              void* d_out, int out_size, void* d_ws, size_t ws_size,
                              hipStream_t stream) {
    const float* in      = (const float*)d_in[0];
    const float* scale_p = (const float*)d_in[1];
    float* out           = (float*)d_out;

    const long long n = (long long)in_sizes[0];

    // a = -((K - n) // 2 + 2), Python floor-division semantics.
    const long long missing = (long long)K_SIZE - n;
    long long fd = missing / 2;
    if ((missing % 2 != 0) && (missing < 0)) fd -= 1;
    const long long a = -(fd + 2);

    const long long n4 = n / 4;
    // Iterations every thread can do unguarded: q0 < STRIDE, so
    // full_iters * STRIDE <= n4 guarantees in-bounds.
    const int full_iters = (int)(n4 / STRIDE);          // 15 for n4 = 2^23

    FlatDilation1D_kernel<<<GRID, BLOCK, 0, stream>>>(
        in, scale_p, (float4*)out, out, n, n4, a, full_iters);
}

// Round 6
// 202.048 us; speedup vs baseline: 1.0765x; 1.0027x over previous
//
#include <hip/hip_runtime.h>
#include <math.h>

#define K_SIZE 41
#define BLOCK 256
#define GRID 2050                       // 2050*256 = 524800 ≡ 0 (mod 41)
#define STRIDE ((long long)BLOCK * GRID)

typedef float vfloat4 __attribute__((ext_vector_type(4)));  // clang-native, ok for nontemporal builtin

// out[k] = base[k % 41]; base[i] = max_{j:|j-20|<=scale} in[a + (i+j)%41].
// Store-BW-bound: 134.2 MB compulsory writes, ~20 µs floor at 6.78 TB/s.
// Per-thread phase r = (4q) mod 41 is invariant because the float4-index
// stride (524800) is ≡ 0 (mod 41) -> pattern value lives in 4 VGPRs and the
// hot loop is one nontemporal global_store_dwordx4 + one add.
__global__ void __launch_bounds__(BLOCK)
FlatDilation1D_kernel(const float* __restrict__ in,
                      const float* __restrict__ scale_p,
                      vfloat4* __restrict__ out4,
                      float* __restrict__ out,
                      long long n, long long n4, long long a,
                      int full_iters) {
    __shared__ float s_pad[K_SIZE];
    __shared__ float s_ext[K_SIZE + 3];
    const int tid = threadIdx.x;

    // ---- preamble: build base[] (+3 wrap entries) ----
    if (tid < K_SIZE) s_pad[tid] = in[a + tid];
    __syncthreads();
    if (tid < K_SIZE) {
        const float scale = *scale_p;
        float m = -INFINITY;
        #pragma unroll
        for (int j = 0; j < K_SIZE; ++j) {
            const float z = -20.0f + (float)j;          // exact in fp32
            if (fabsf(z) <= scale) {
                int idx = tid + j;
                if (idx >= K_SIZE) idx -= K_SIZE;
                m = fmaxf(m, s_pad[idx]);
            }
        }
        s_ext[tid] = m;
    }
    __syncthreads();
    if (tid < 3) s_ext[K_SIZE + tid] = s_ext[tid];
    __syncthreads();

    // ---- per-thread constant pattern value ----
    long long q = (long long)blockIdx.x * BLOCK + tid;  // first float4 index
    // element index of this float4 is 4q -> phase r = (4q) mod 41.
    const unsigned int r = (4u * (unsigned int)q) % 41u;  // loop-invariant
    vfloat4 v;
    v.x = s_ext[r];
    v.y = s_ext[r + 1];
    v.z = s_ext[r + 2];
    v.w = s_ext[r + 3];

    // ---- hot loop: pure streaming nontemporal stores, no guards, no LDS ----
    #pragma unroll 4
    for (int it = 0; it < full_iters; ++it) {           // provably in-bounds
        __builtin_nontemporal_store(v, &out4[q]);
        q += STRIDE;
    }
    while (q < n4) {                                    // last partial sweep
        __builtin_nontemporal_store(v, &out4[q]);
        q += STRIDE;
    }

    // ---- scalar tail (n % 4 elements; 1 for this N) ----
    if (blockIdx.x == 0 && tid == 0) {
        for (long long k = n4 * 4; k < n; ++k) {
            out[k] = s_ext[(unsigned int)(((unsigned long long)k) % 41ull)];
        }
    }
}

extern "C" void kernel_launch(void* const* d_in, const int* in_sizes, int n_in,
                              void* d_out, int out_size, void* d_ws, size_t ws_size,
                              hipStream_t stream) {
    const float* in      = (const float*)d_in[0];
    const float* scale_p = (const float*)d_in[1];
    float* out           = (float*)d_out;

    const long long n = (long long)in_sizes[0];

    // a = -((K - n) // 2 + 2), Python floor-division semantics.
    const long long missing = (long long)K_SIZE - n;
    long long fd = missing / 2;
    if ((missing % 2 != 0) && (missing < 0)) fd -= 1;
    const long long a = -(fd + 2);

    const long long n4 = n / 4;
    // Iterations every thread can do unguarded: q0 < STRIDE, so
    // full_iters * STRIDE <= n4 guarantees in-bounds.
    const int full_iters = (int)(n4 / STRIDE);          // 15 for n4 = 2^23

    FlatDilation1D_kernel<<<GRID, BLOCK, 0, stream>>>(
        in, scale_p, (vfloat4*)out, out, n, n4, a, full_iters);
}